// Round 2
// baseline (176.118 us; speedup 1.0000x reference)
//
#include <hip/hip_runtime.h>

#define NROWS  32768
#define NBLK   2048

// db8 dec filters, pre-reversed for convolution (out[i] = sum_k in[2i+k-14]*F[k])
__device__ constexpr float GG[16] = {
    0.05441584224308161f,     0.3128715909144659f,     0.6756307362980128f,    0.5853546836548691f,
   -0.015829105256023893f,   -0.2840155429624281f,     0.00047248457399797254f,0.128747426620186f,
   -0.01736930100202211f,    -0.04408825393106472f,    0.013981027917015516f,  0.008746094047015655f,
   -0.00487035299301066f,    -0.0003917403729959771f,  0.0006754494059985568f,-0.00011747678400228192f
};
__device__ constexpr float HH[16] = {
   -0.00011747678400228192f, -0.0006754494059985568f, -0.0003917403729959771f, 0.00487035299301066f,
    0.008746094047015655f,   -0.013981027917015516f,  -0.04408825393106472f,   0.01736930100202211f,
    0.128747426620186f,      -0.00047248457399797254f,-0.2840155429624281f,    0.015829105256023893f,
    0.5853546836548691f,     -0.6756307362980128f,     0.3128715909144659f,   -0.05441584224308161f
};

// lgkm-only barrier: syncs LDS without draining outstanding global loads (register prefetch survives)
__device__ __forceinline__ void bar_lgkm() {
    asm volatile("s_waitcnt lgkmcnt(0)" ::: "memory");
    __builtin_amdgcn_s_barrier();
    asm volatile("" ::: "memory");
}

// One DWT level, parity-split layout. Input: EB/OB with data at [8+u] (E[u]=in[2u], O[u]=in[2u+1]),
// front pads [1..7], tail pads after data. Lane g computes outputs 4g..4g+3.
// out[i] = sum_c E[i-7+c]*F[2c] + O[i-7+c]*F[2c+1]; window buf idx [4g, 4g+12).
// Returns sum of valid d^2. If STORE, writes a-outputs (data + mirror pads) for next level.
template<int M, bool STORE>
__device__ __forceinline__ float do_level(const float* __restrict__ EB, const float* __restrict__ OB,
                                          float* __restrict__ EBn, float* __restrict__ OBn, int g)
{
    float wE[12], wO[12];
    {
        const float4* pe = (const float4*)(EB + 4 * g);
        float4 q0 = pe[0], q1 = pe[1], q2 = pe[2];
        wE[0]=q0.x; wE[1]=q0.y; wE[2]=q0.z; wE[3]=q0.w;
        wE[4]=q1.x; wE[5]=q1.y; wE[6]=q1.z; wE[7]=q1.w;
        wE[8]=q2.x; wE[9]=q2.y; wE[10]=q2.z; wE[11]=q2.w;
        const float4* po = (const float4*)(OB + 4 * g);
        float4 r0 = po[0], r1 = po[1], r2 = po[2];
        wO[0]=r0.x; wO[1]=r0.y; wO[2]=r0.z; wO[3]=r0.w;
        wO[4]=r1.x; wO[5]=r1.y; wO[6]=r1.z; wO[7]=r1.w;
        wO[8]=r2.x; wO[9]=r2.y; wO[10]=r2.z; wO[11]=r2.w;
    }
    float aj[4] = {0.f,0.f,0.f,0.f}, dj[4] = {0.f,0.f,0.f,0.f};
#pragma unroll
    for (int c = 0; c < 8; ++c) {
        const float ge = GG[2*c], go = GG[2*c+1];
        const float he = HH[2*c], ho = HH[2*c+1];
#pragma unroll
        for (int j = 0; j < 4; ++j) {
            const float we = wE[j+1+c], wo = wO[j+1+c];
            aj[j] = fmaf(we, ge, aj[j]);
            aj[j] = fmaf(wo, go, aj[j]);
            dj[j] = fmaf(we, he, dj[j]);
            dj[j] = fmaf(wo, ho, dj[j]);
        }
    }
    const int i0 = 4 * g;
    float ds = dj[0] * dj[0];                       // i0 < M always (g < ceil(M/4))
    if (i0 + 1 < M) ds += dj[1] * dj[1];
    if (i0 + 2 < M) ds += dj[2] * dj[2];
    if (i0 + 3 < M) ds += dj[3] * dj[3];
    if (STORE) {
        if (i0 + 3 < M) {
            *(float2*)(EBn + 8 + 2 * g) = make_float2(aj[0], aj[2]);   // out[4g], out[4g+2]
            *(float2*)(OBn + 8 + 2 * g) = make_float2(aj[1], aj[3]);   // out[4g+1], out[4g+3]
        } else {
            EBn[8 + 2 * g] = aj[0];
            if (i0 + 1 < M) OBn[8 + 2 * g] = aj[1];
            if (i0 + 2 < M) EBn[8 + 2 * g + 1] = aj[2];
            if (i0 + 3 < M) OBn[8 + 2 * g + 1] = aj[3];
        }
        if (g < 4) {  // front mirror pads: out[0..13] -> reflected slots
#pragma unroll
            for (int j = 0; j < 4; ++j) {
                int i = i0 + j;
                if (i <= 13) {
                    if (i & 1) EBn[(15 - i) >> 1] = aj[j];
                    else       OBn[(14 - i) >> 1] = aj[j];
                }
            }
        }
        constexpr int LAM = (M - 1) / 2;  // M odd for all stored levels
        if (i0 + 3 >= M - 15) {  // tail mirror pads: out[M-15..M-1]
#pragma unroll
            for (int j = 0; j < 4; ++j) {
                int i = i0 + j;
                if (i >= M - 15 && i < M) {
                    if (i & 1) EBn[8 + LAM + ((M - i) >> 1)]     = aj[j];
                    else       OBn[8 + LAM + ((M - 1 - i) >> 1)] = aj[j];
                }
            }
        }
    }
    return ds;
}

__global__ __launch_bounds__(256, 6) void combined_loss_kernel(
    const float* __restrict__ x, const float* __restrict__ y,
    float* __restrict__ partials)
{
    // level buffers: E/O split, data at [8+u]; sizes cover window over-reads
    __shared__ __align__(16) float E0b[528], O0b[528];   // L=1024: E/O 512 each + pads
    __shared__ __align__(16) float E1b[280], O1b[280];   // M=519: reads to idx 275
    __shared__ __align__(16) float E2b[152], O2b[152];   // M=267: reads to idx 151
    __shared__ float bnd[6];
    __shared__ float wsum[4];

    const int tid = threadIdx.x;
    float s_mse = 0.f, s_spec = 0.f, s_d1 = 0.f, s_d2 = 0.f, s_d3 = 0.f;

    const float4* xp = (const float4*)x;
    const float4* yp = (const float4*)y;

    int row = blockIdx.x;
    float4 px = xp[(size_t)row * 256 + tid];
    float4 py = yp[(size_t)row * 256 + tid];

#pragma unroll 1
    for (; row < NROWS; row += NBLK) {
        const float4 xv = px, yv = py;
        const int nrow = row + NBLK;
        if (nrow < NROWS) {  // uniform branch; loads consumed next iteration (latency hidden by 3 phases)
            px = xp[(size_t)nrow * 256 + tid];
            py = yp[(size_t)nrow * 256 + tid];
        }
        const float4 ev = make_float4(xv.x - yv.x, xv.y - yv.y, xv.z - yv.z, xv.w - yv.w);
        s_mse += ev.x * ev.x + ev.y * ev.y + ev.z * ev.z + ev.w * ev.w;

        // parity-split store: E[2t]=e[4t], E[2t+1]=e[4t+2]; O[2t]=e[4t+1], O[2t+1]=e[4t+3]
        *(float2*)(E0b + 8 + 2 * tid) = make_float2(ev.x, ev.z);
        *(float2*)(O0b + 8 + 2 * tid) = make_float2(ev.y, ev.w);
        if (tid < 4) {   // front pads (reflection of e[0..13])
            E0b[7 - 2 * tid] = ev.y;  O0b[7 - 2 * tid] = ev.x;
            if (tid < 3) { E0b[6 - 2 * tid] = ev.w;  O0b[6 - 2 * tid] = ev.z; }
        }
        if (tid >= 252) { // tail pads (reflection of e[1009..1023])
            const int iy = 1031 - 2 * tid;
            const int iw = 1030 - 2 * tid;
            if (iy <= 527) E0b[iy] = ev.y;
            if (iy <= 526) O0b[iy] = ev.x;
            E0b[iw] = ev.w;
            O0b[iw] = ev.z;
        }
        if ((tid & 63) == 0 && tid) {   // cross-wave boundary for spectral
            bnd[((tid >> 6) - 1) * 2]     = xv.x;
            bnd[((tid >> 6) - 1) * 2 + 1] = xv.y;
        }
        bar_lgkm();  // S1

        // spectral: sd_i = x[i] - 2x[i+1] + x[i+2]; thread owns i = 4t..4t+3 (i <= 1021)
        {
            float n0 = __shfl_down(xv.x, 1, 64);
            float n1 = __shfl_down(xv.y, 1, 64);
            if ((tid & 63) == 63 && tid < 255) {
                n0 = bnd[(tid >> 6) * 2];
                n1 = bnd[(tid >> 6) * 2 + 1];
            }
            float sd0 = xv.x - 2.f * xv.y + xv.z;
            float sd1 = xv.y - 2.f * xv.z + xv.w;
            s_spec += sd0 * sd0 + sd1 * sd1;
            if (tid < 255) {
                float sd2 = xv.z - 2.f * xv.w + n0;
                float sd3 = xv.w - 2.f * n0 + n1;
                s_spec += sd2 * sd2 + sd3 * sd3;
            }
        }

        if (tid < 130) s_d1 += do_level<519, true>(E0b, O0b, E1b, O1b, tid);
        bar_lgkm();  // S2
        if (tid < 67)  s_d2 += do_level<267, true>(E1b, O1b, E2b, O2b, tid);
        bar_lgkm();  // S3
        if (tid < 36)  s_d3 += do_level<141, false>(E2b, O2b, E2b, O2b, tid);
        // no barrier: next iter writes only E0b/O0b/bnd (disjoint from E2b/O2b reads);
        // E0b/O0b/bnd readers of this iter finished before S2 (guaranteed since any wave
        // past S3 implies all waves past S2).
    }

    const float wm  = 1.0f / 33554432.0f;             // 32*1024*1024
    const float wsp = 1.0f / 33488896.0f;             // 32*1024*1022
    const float w1  = 1.0f / (3.0f * 17006592.0f);    // 32768*519
    const float w2  = 1.0f / (3.0f * 8749056.0f);     // 32768*267
    const float w3  = 1.0f / (3.0f * 4620288.0f);     // 32768*141
    float local = wm * s_mse + wsp * s_spec + w1 * s_d1 + w2 * s_d2 + w3 * s_d3;

#pragma unroll
    for (int off = 32; off > 0; off >>= 1)
        local += __shfl_down(local, off, 64);
    __syncthreads();
    if ((tid & 63) == 0) wsum[tid >> 6] = local;
    __syncthreads();
    if (tid == 0) partials[blockIdx.x] = wsum[0] + wsum[1] + wsum[2] + wsum[3];
}

__global__ __launch_bounds__(256) void reduce_kernel(const float* __restrict__ partials,
                                                     int n, float* __restrict__ out)
{
    __shared__ double sm[256];
    double s = 0.0;
    for (int i = threadIdx.x; i < n; i += 256) s += (double)partials[i];
    sm[threadIdx.x] = s;
    __syncthreads();
    for (int off = 128; off > 0; off >>= 1) {
        if (threadIdx.x < off) sm[threadIdx.x] += sm[threadIdx.x + off];
        __syncthreads();
    }
    if (threadIdx.x == 0) out[0] = (float)sm[0];
}

extern "C" void kernel_launch(void* const* d_in, const int* in_sizes, int n_in,
                              void* d_out, int out_size, void* d_ws, size_t ws_size,
                              hipStream_t stream) {
    const float* x = (const float*)d_in[0];   // output
    const float* y = (const float*)d_in[1];   // target
    float* partials = (float*)d_ws;           // NBLK floats
    combined_loss_kernel<<<NBLK, 256, 0, stream>>>(x, y, partials);
    reduce_kernel<<<1, 256, 0, stream>>>(partials, NBLK, (float*)d_out);
}

// Round 3
// 91.864 us; speedup vs baseline: 1.9172x; 1.9172x over previous
//
#include <hip/hip_runtime.h>

#define NROWS  32768
#define NBLK   2048

// db8 dec filters, pre-reversed for convolution (out[i] = sum_k in[2i+k-14]*F[k])
__device__ constexpr float GG[16] = {
    0.05441584224308161f,     0.3128715909144659f,     0.6756307362980128f,    0.5853546836548691f,
   -0.015829105256023893f,   -0.2840155429624281f,     0.00047248457399797254f,0.128747426620186f,
   -0.01736930100202211f,    -0.04408825393106472f,    0.013981027917015516f,  0.008746094047015655f,
   -0.00487035299301066f,    -0.0003917403729959771f,  0.0006754494059985568f,-0.00011747678400228192f
};
__device__ constexpr float HH[16] = {
   -0.00011747678400228192f, -0.0006754494059985568f, -0.0003917403729959771f, 0.00487035299301066f,
    0.008746094047015655f,   -0.013981027917015516f,  -0.04408825393106472f,   0.01736930100202211f,
    0.128747426620186f,      -0.00047248457399797254f,-0.2840155429624281f,    0.015829105256023893f,
    0.5853546836548691f,     -0.6756307362980128f,     0.3128715909144659f,   -0.05441584224308161f
};

// lgkm-only barrier: syncs LDS without draining outstanding global loads (register prefetch survives)
__device__ __forceinline__ void bar_lgkm() {
    asm volatile("s_waitcnt lgkmcnt(0)" ::: "memory");
    __builtin_amdgcn_s_barrier();
    asm volatile("" ::: "memory");
}

// One DWT level, parity-split layout. Input: EB/OB with data at [8+u] (E[u]=in[2u], O[u]=in[2u+1]),
// front pads [1..7], tail pads after data. Lane g computes outputs 4g..4g+3.
// out[i] = sum_c E[i-7+c]*F[2c] + O[i-7+c]*F[2c+1]; window buf idx [4g, 4g+12).
// Returns sum of valid d^2. If STORE, writes a-outputs (data + mirror pads) for next level.
template<int M, bool STORE>
__device__ __forceinline__ float do_level(const float* __restrict__ EB, const float* __restrict__ OB,
                                          float* __restrict__ EBn, float* __restrict__ OBn, int g)
{
    float wE[12], wO[12];
    {
        const float4* pe = (const float4*)(EB + 4 * g);
        float4 q0 = pe[0], q1 = pe[1], q2 = pe[2];
        wE[0]=q0.x; wE[1]=q0.y; wE[2]=q0.z; wE[3]=q0.w;
        wE[4]=q1.x; wE[5]=q1.y; wE[6]=q1.z; wE[7]=q1.w;
        wE[8]=q2.x; wE[9]=q2.y; wE[10]=q2.z; wE[11]=q2.w;
        const float4* po = (const float4*)(OB + 4 * g);
        float4 r0 = po[0], r1 = po[1], r2 = po[2];
        wO[0]=r0.x; wO[1]=r0.y; wO[2]=r0.z; wO[3]=r0.w;
        wO[4]=r1.x; wO[5]=r1.y; wO[6]=r1.z; wO[7]=r1.w;
        wO[8]=r2.x; wO[9]=r2.y; wO[10]=r2.z; wO[11]=r2.w;
    }
    float aj[4] = {0.f,0.f,0.f,0.f}, dj[4] = {0.f,0.f,0.f,0.f};
#pragma unroll
    for (int c = 0; c < 8; ++c) {
        const float ge = GG[2*c], go = GG[2*c+1];
        const float he = HH[2*c], ho = HH[2*c+1];
#pragma unroll
        for (int j = 0; j < 4; ++j) {
            const float we = wE[j+1+c], wo = wO[j+1+c];
            aj[j] = fmaf(we, ge, aj[j]);
            aj[j] = fmaf(wo, go, aj[j]);
            dj[j] = fmaf(we, he, dj[j]);
            dj[j] = fmaf(wo, ho, dj[j]);
        }
    }
    const int i0 = 4 * g;
    float ds = dj[0] * dj[0];                       // i0 < M always (g < ceil(M/4))
    if (i0 + 1 < M) ds += dj[1] * dj[1];
    if (i0 + 2 < M) ds += dj[2] * dj[2];
    if (i0 + 3 < M) ds += dj[3] * dj[3];
    if (STORE) {
        if (i0 + 3 < M) {
            *(float2*)(EBn + 8 + 2 * g) = make_float2(aj[0], aj[2]);   // out[4g], out[4g+2]
            *(float2*)(OBn + 8 + 2 * g) = make_float2(aj[1], aj[3]);   // out[4g+1], out[4g+3]
        } else {
            EBn[8 + 2 * g] = aj[0];
            if (i0 + 1 < M) OBn[8 + 2 * g] = aj[1];
            if (i0 + 2 < M) EBn[8 + 2 * g + 1] = aj[2];
            if (i0 + 3 < M) OBn[8 + 2 * g + 1] = aj[3];
        }
        if (g < 4) {  // front mirror pads: out[0..13] -> reflected slots
#pragma unroll
            for (int j = 0; j < 4; ++j) {
                int i = i0 + j;
                if (i <= 13) {
                    if (i & 1) EBn[(15 - i) >> 1] = aj[j];
                    else       OBn[(14 - i) >> 1] = aj[j];
                }
            }
        }
        constexpr int LAM = (M - 1) / 2;  // M odd for all stored levels
        if (i0 + 3 >= M - 15) {  // tail mirror pads: out[M-15..M-1]
#pragma unroll
            for (int j = 0; j < 4; ++j) {
                int i = i0 + j;
                if (i >= M - 15 && i < M) {
                    if (i & 1) EBn[8 + LAM + ((M - i) >> 1)]     = aj[j];
                    else       OBn[8 + LAM + ((M - 1 - i) >> 1)] = aj[j];
                }
            }
        }
    }
    return ds;
}

__global__ __launch_bounds__(256) void combined_loss_kernel(
    const float* __restrict__ x, const float* __restrict__ y,
    float* __restrict__ partials)
{
    // level buffers: E/O split, data at [8+u]; sizes cover window over-reads
    __shared__ __align__(16) float E0b[528], O0b[528];   // L=1024: E/O 512 each + pads
    __shared__ __align__(16) float E1b[280], O1b[280];   // M=519: reads to idx 275
    __shared__ __align__(16) float E2b[152], O2b[152];   // M=267: reads to idx 151
    __shared__ float bnd[6];
    __shared__ float wsum[4];

    const int tid = threadIdx.x;
    float s_mse = 0.f, s_spec = 0.f, s_d1 = 0.f, s_d2 = 0.f, s_d3 = 0.f;

    const float4* xp = (const float4*)x;
    const float4* yp = (const float4*)y;

    int row = blockIdx.x;
    float4 px = xp[(size_t)row * 256 + tid];
    float4 py = yp[(size_t)row * 256 + tid];

#pragma unroll 1
    for (; row < NROWS; row += NBLK) {
        const float4 xv = px, yv = py;
        const int nrow = row + NBLK;
        if (nrow < NROWS) {  // uniform branch; loads consumed next iteration (latency hidden by 3 phases)
            px = xp[(size_t)nrow * 256 + tid];
            py = yp[(size_t)nrow * 256 + tid];
        }
        const float4 ev = make_float4(xv.x - yv.x, xv.y - yv.y, xv.z - yv.z, xv.w - yv.w);
        s_mse += ev.x * ev.x + ev.y * ev.y + ev.z * ev.z + ev.w * ev.w;

        // parity-split store: E[2t]=e[4t], E[2t+1]=e[4t+2]; O[2t]=e[4t+1], O[2t+1]=e[4t+3]
        *(float2*)(E0b + 8 + 2 * tid) = make_float2(ev.x, ev.z);
        *(float2*)(O0b + 8 + 2 * tid) = make_float2(ev.y, ev.w);
        if (tid < 4) {   // front pads (reflection of e[0..13])
            E0b[7 - 2 * tid] = ev.y;  O0b[7 - 2 * tid] = ev.x;
            if (tid < 3) { E0b[6 - 2 * tid] = ev.w;  O0b[6 - 2 * tid] = ev.z; }
        }
        if (tid >= 252) { // tail pads (reflection of e[1009..1023])
            const int iy = 1031 - 2 * tid;
            const int iw = 1030 - 2 * tid;
            if (iy <= 527) E0b[iy] = ev.y;
            if (iy <= 526) O0b[iy] = ev.x;
            E0b[iw] = ev.w;
            O0b[iw] = ev.z;
        }
        if ((tid & 63) == 0 && tid) {   // cross-wave boundary for spectral
            bnd[((tid >> 6) - 1) * 2]     = xv.x;
            bnd[((tid >> 6) - 1) * 2 + 1] = xv.y;
        }
        bar_lgkm();  // S1

        // spectral: sd_i = x[i] - 2x[i+1] + x[i+2]; thread owns i = 4t..4t+3 (i <= 1021)
        {
            float n0 = __shfl_down(xv.x, 1, 64);
            float n1 = __shfl_down(xv.y, 1, 64);
            if ((tid & 63) == 63 && tid < 255) {
                n0 = bnd[(tid >> 6) * 2];
                n1 = bnd[(tid >> 6) * 2 + 1];
            }
            float sd0 = xv.x - 2.f * xv.y + xv.z;
            float sd1 = xv.y - 2.f * xv.z + xv.w;
            s_spec += sd0 * sd0 + sd1 * sd1;
            if (tid < 255) {
                float sd2 = xv.z - 2.f * xv.w + n0;
                float sd3 = xv.w - 2.f * n0 + n1;
                s_spec += sd2 * sd2 + sd3 * sd3;
            }
        }

        if (tid < 130) s_d1 += do_level<519, true>(E0b, O0b, E1b, O1b, tid);
        bar_lgkm();  // S2
        if (tid < 67)  s_d2 += do_level<267, true>(E1b, O1b, E2b, O2b, tid);
        bar_lgkm();  // S3
        if (tid < 36)  s_d3 += do_level<141, false>(E2b, O2b, E2b, O2b, tid);
        // no barrier: next iter writes only E0b/O0b/bnd (disjoint from E2b/O2b reads);
        // E0b/O0b/bnd readers of this iter finished before S2 (guaranteed since any wave
        // past S3 implies all waves past S2).
    }

    const float wm  = 1.0f / 33554432.0f;             // 32*1024*1024
    const float wsp = 1.0f / 33488896.0f;             // 32*1024*1022
    const float w1  = 1.0f / (3.0f * 17006592.0f);    // 32768*519
    const float w2  = 1.0f / (3.0f * 8749056.0f);    // 32768*267
    const float w3  = 1.0f / (3.0f * 4620288.0f);    // 32768*141
    float local = wm * s_mse + wsp * s_spec + w1 * s_d1 + w2 * s_d2 + w3 * s_d3;

#pragma unroll
    for (int off = 32; off > 0; off >>= 1)
        local += __shfl_down(local, off, 64);
    __syncthreads();
    if ((tid & 63) == 0) wsum[tid >> 6] = local;
    __syncthreads();
    if (tid == 0) partials[blockIdx.x] = wsum[0] + wsum[1] + wsum[2] + wsum[3];
}

__global__ __launch_bounds__(256) void reduce_kernel(const float* __restrict__ partials,
                                                     int n, float* __restrict__ out)
{
    __shared__ double sm[256];
    double s = 0.0;
    for (int i = threadIdx.x; i < n; i += 256) s += (double)partials[i];
    sm[threadIdx.x] = s;
    __syncthreads();
    for (int off = 128; off > 0; off >>= 1) {
        if (threadIdx.x < off) sm[threadIdx.x] += sm[threadIdx.x + off];
        __syncthreads();
    }
    if (threadIdx.x == 0) out[0] = (float)sm[0];
}

extern "C" void kernel_launch(void* const* d_in, const int* in_sizes, int n_in,
                              void* d_out, int out_size, void* d_ws, size_t ws_size,
                              hipStream_t stream) {
    const float* x = (const float*)d_in[0];   // output
    const float* y = (const float*)d_in[1];   // target
    float* partials = (float*)d_ws;           // NBLK floats
    combined_loss_kernel<<<NBLK, 256, 0, stream>>>(x, y, partials);
    reduce_kernel<<<1, 256, 0, stream>>>(partials, NBLK, (float*)d_out);
}

// Round 4
// 78.148 us; speedup vs baseline: 2.2536x; 1.1755x over previous
//
#include <hip/hip_runtime.h>

#define NROWS 32768
#define NBLK  8192   // 4 waves/block, 1 row per wave

// db8 dec filters, pre-reversed for convolution (out[i] = sum_k in[2i+k-14]*F[k])
__device__ constexpr float GG[16] = {
    0.05441584224308161f,     0.3128715909144659f,     0.6756307362980128f,    0.5853546836548691f,
   -0.015829105256023893f,   -0.2840155429624281f,     0.00047248457399797254f,0.128747426620186f,
   -0.01736930100202211f,    -0.04408825393106472f,    0.013981027917015516f,  0.008746094047015655f,
   -0.00487035299301066f,    -0.0003917403729959771f,  0.0006754494059985568f,-0.00011747678400228192f
};
__device__ constexpr float HH[16] = {
   -0.00011747678400228192f, -0.0006754494059985568f, -0.0003917403729959771f, 0.00487035299301066f,
    0.008746094047015655f,   -0.013981027917015516f,  -0.04408825393106472f,   0.01736930100202211f,
    0.128747426620186f,      -0.00047248457399797254f,-0.2840155429624281f,    0.015829105256023893f,
    0.5853546836548691f,     -0.6756307362980128f,     0.3128715909144659f,   -0.05441584224308161f
};

// wave-internal LDS ordering only — NO barrier (waves are independent)
__device__ __forceinline__ void wave_lgkm0() {
    asm volatile("s_waitcnt lgkmcnt(0)" ::: "memory");
}

// One DWT level, parity-split layout. EB/OB hold data at [8+u] (E[u]=in[2u], O[u]=in[2u+1]),
// front pads [1..7], tail pads after data. Group g computes outputs 4g..4g+3.
// out[i] = sum_c E[i-7+c]*F[2c] + O[i-7+c]*F[2c+1]; window buf idx [4g, 4g+12).
template<int M, bool STORE>
__device__ __forceinline__ float do_level(const float* __restrict__ EB, const float* __restrict__ OB,
                                          float* __restrict__ EBn, float* __restrict__ OBn, int g)
{
    float wE[12], wO[12];
    {
        const float4* pe = (const float4*)(EB + 4 * g);
        float4 q0 = pe[0], q1 = pe[1], q2 = pe[2];
        wE[0]=q0.x; wE[1]=q0.y; wE[2]=q0.z; wE[3]=q0.w;
        wE[4]=q1.x; wE[5]=q1.y; wE[6]=q1.z; wE[7]=q1.w;
        wE[8]=q2.x; wE[9]=q2.y; wE[10]=q2.z; wE[11]=q2.w;
        const float4* po = (const float4*)(OB + 4 * g);
        float4 r0 = po[0], r1 = po[1], r2 = po[2];
        wO[0]=r0.x; wO[1]=r0.y; wO[2]=r0.z; wO[3]=r0.w;
        wO[4]=r1.x; wO[5]=r1.y; wO[6]=r1.z; wO[7]=r1.w;
        wO[8]=r2.x; wO[9]=r2.y; wO[10]=r2.z; wO[11]=r2.w;
    }
    float aj[4] = {0.f,0.f,0.f,0.f}, dj[4] = {0.f,0.f,0.f,0.f};
#pragma unroll
    for (int c = 0; c < 8; ++c) {
        const float ge = GG[2*c], go = GG[2*c+1];
        const float he = HH[2*c], ho = HH[2*c+1];
#pragma unroll
        for (int j = 0; j < 4; ++j) {
            const float we = wE[j+1+c], wo = wO[j+1+c];
            aj[j] = fmaf(we, ge, aj[j]);
            aj[j] = fmaf(wo, go, aj[j]);
            dj[j] = fmaf(we, he, dj[j]);
            dj[j] = fmaf(wo, ho, dj[j]);
        }
    }
    const int i0 = 4 * g;
    float ds = dj[0] * dj[0];
    if (i0 + 1 < M) ds += dj[1] * dj[1];
    if (i0 + 2 < M) ds += dj[2] * dj[2];
    if (i0 + 3 < M) ds += dj[3] * dj[3];
    if (STORE) {
        if (i0 + 3 < M) {
            *(float2*)(EBn + 8 + 2 * g) = make_float2(aj[0], aj[2]);
            *(float2*)(OBn + 8 + 2 * g) = make_float2(aj[1], aj[3]);
        } else {
            EBn[8 + 2 * g] = aj[0];
            if (i0 + 1 < M) OBn[8 + 2 * g] = aj[1];
            if (i0 + 2 < M) EBn[8 + 2 * g + 1] = aj[2];
            if (i0 + 3 < M) OBn[8 + 2 * g + 1] = aj[3];
        }
        if (g < 4) {  // front mirror pads: out[0..13] -> reflected slots
#pragma unroll
            for (int j = 0; j < 4; ++j) {
                int i = i0 + j;
                if (i <= 13) {
                    if (i & 1) EBn[(15 - i) >> 1] = aj[j];
                    else       OBn[(14 - i) >> 1] = aj[j];
                }
            }
        }
        constexpr int LAM = (M - 1) / 2;
        if (i0 + 3 >= M - 15) {  // tail mirror pads: out[M-15..M-1]
#pragma unroll
            for (int j = 0; j < 4; ++j) {
                int i = i0 + j;
                if (i >= M - 15 && i < M) {
                    if (i & 1) EBn[8 + LAM + ((M - i) >> 1)]     = aj[j];
                    else       OBn[8 + LAM + ((M - 1 - i) >> 1)] = aj[j];
                }
            }
        }
    }
    return ds;
}

__global__ __launch_bounds__(256) void combined_loss_kernel(
    const float* __restrict__ x, const float* __restrict__ y,
    float* __restrict__ partials)
{
    // per-wave slice: E0[0..527] O0[528..1055] E1[1056..1331] O1[1332..1607]
    // E2/O2 alias E0/O0 (dead after level 1)  -> 6432 B/wave, 25.7 KB/block
    __shared__ __align__(16) float lds[4][1608];
    __shared__ float wsum[4];

    const int tid  = threadIdx.x;
    const int wid  = tid >> 6;
    const int lane = tid & 63;
    float* const W  = lds[wid];
    float* const E0 = W;
    float* const O0 = W + 528;
    float* const E1 = W + 1056;
    float* const O1 = W + 1332;
    float* const E2 = W;          // alias
    float* const O2 = W + 528;    // alias

    const int row = blockIdx.x * 4 + wid;
    const float4* xp = (const float4*)x + (size_t)row * 256;
    const float4* yp = (const float4*)y + (size_t)row * 256;

    float4 xc[4];
    float s_mse = 0.f, s_spec = 0.f;

#pragma unroll
    for (int c = 0; c < 4; ++c) {
        const float4 xv = xp[c * 64 + lane];
        const float4 yv = yp[c * 64 + lane];
        xc[c] = xv;
        const float4 ev = make_float4(xv.x - yv.x, xv.y - yv.y, xv.z - yv.z, xv.w - yv.w);
        s_mse += ev.x * ev.x + ev.y * ev.y + ev.z * ev.z + ev.w * ev.w;
        const int u = c * 64 + lane;
        *(float2*)(E0 + 8 + 2 * u) = make_float2(ev.x, ev.z);
        *(float2*)(O0 + 8 + 2 * u) = make_float2(ev.y, ev.w);
        if (c == 0 && lane < 4) {   // front pads (reflection of e[0..13])
            E0[7 - 2 * lane] = ev.y;  O0[7 - 2 * lane] = ev.x;
            if (lane < 3) { E0[6 - 2 * lane] = ev.w;  O0[6 - 2 * lane] = ev.z; }
        }
        if (c == 3 && lane >= 60) { // tail pads (reflection of e[1009..1023])
            const int iy = 1031 - 2 * u;
            const int iw = 1030 - 2 * u;
            if (iy <= 527) E0[iy] = ev.y;
            if (iy <= 526) O0[iy] = ev.x;
            E0[iw] = ev.w;
            O0[iw] = ev.z;
        }
    }

    // spectral: sd_i = x[i] - 2x[i+1] + x[i+2]; lane owns i = 4u..4u+3 (u = 64c+lane), i <= 1021
#pragma unroll
    for (int c = 0; c < 4; ++c) {
        const float4 xv = xc[c];
        float n0 = __shfl_down(xv.x, 1, 64);
        float n1 = __shfl_down(xv.y, 1, 64);
        if (c < 3) {
            const float b0 = __shfl(xc[c + 1].x, 0, 64);   // all lanes execute
            const float b1 = __shfl(xc[c + 1].y, 0, 64);
            if (lane == 63) { n0 = b0; n1 = b1; }
        }
        const float sd0 = xv.x - 2.f * xv.y + xv.z;
        const float sd1 = xv.y - 2.f * xv.z + xv.w;
        s_spec += sd0 * sd0 + sd1 * sd1;
        const float sd2 = xv.z - 2.f * xv.w + n0;
        const float sd3 = xv.w - 2.f * n0 + n1;
        if (c < 3 || lane < 63)
            s_spec += sd2 * sd2 + sd3 * sd3;
    }

    float s_d1 = 0.f, s_d2 = 0.f, s_d3 = 0.f;
    wave_lgkm0();
    for (int g = lane; g < 130; g += 64) s_d1 += do_level<519, true>(E0, O0, E1, O1, g);
    wave_lgkm0();
    for (int g = lane; g < 67;  g += 64) s_d2 += do_level<267, true>(E1, O1, E2, O2, g);
    wave_lgkm0();
    if (lane < 36)                       s_d3 += do_level<141, false>(E2, O2, E2, O2, lane);

    const float wm  = 1.0f / 33554432.0f;             // 32*1024*1024
    const float wsp = 1.0f / 33488896.0f;             // 32*1024*1022
    const float w1  = 1.0f / (3.0f * 17006592.0f);    // 32768*519
    const float w2  = 1.0f / (3.0f * 8749056.0f);     // 32768*267
    const float w3  = 1.0f / (3.0f * 4620288.0f);     // 32768*141
    float local = wm * s_mse + wsp * s_spec + w1 * s_d1 + w2 * s_d2 + w3 * s_d3;

#pragma unroll
    for (int off = 32; off > 0; off >>= 1)
        local += __shfl_down(local, off, 64);
    if (lane == 0) wsum[wid] = local;
    __syncthreads();
    if (tid == 0) partials[blockIdx.x] = wsum[0] + wsum[1] + wsum[2] + wsum[3];
}

__global__ __launch_bounds__(256) void reduce_kernel(const float* __restrict__ partials,
                                                     int n, float* __restrict__ out)
{
    __shared__ double sm[256];
    double s = 0.0;
    for (int i = threadIdx.x; i < n; i += 256) s += (double)partials[i];
    sm[threadIdx.x] = s;
    __syncthreads();
    for (int off = 128; off > 0; off >>= 1) {
        if (threadIdx.x < off) sm[threadIdx.x] += sm[threadIdx.x + off];
        __syncthreads();
    }
    if (threadIdx.x == 0) out[0] = (float)sm[0];
}

extern "C" void kernel_launch(void* const* d_in, const int* in_sizes, int n_in,
                              void* d_out, int out_size, void* d_ws, size_t ws_size,
                              hipStream_t stream) {
    const float* x = (const float*)d_in[0];   // output
    const float* y = (const float*)d_in[1];   // target
    float* partials = (float*)d_ws;           // NBLK floats (32 KB)
    combined_loss_kernel<<<NBLK, 256, 0, stream>>>(x, y, partials);
    reduce_kernel<<<1, 256, 0, stream>>>(partials, NBLK, (float*)d_out);
}

// Round 5
// 55.229 us; speedup vs baseline: 3.1889x; 1.4150x over previous
//
#include <hip/hip_runtime.h>

#define NROWS 32768
#define NBLK  8192   // 4 waves/block, 1 row per wave

typedef _Float16 h2 __attribute__((ext_vector_type(2)));

// db8 dec filters, pre-reversed (out[i] = sum_k in[2i+k-14]*F[k]), packed as f16 pairs
#define H2C(a,b) {(_Float16)(a##f), (_Float16)(b##f)}

__device__ __forceinline__ float DOT2(unsigned w, h2 f, float acc) {
#if __has_builtin(__builtin_amdgcn_fdot2)
    return __builtin_amdgcn_fdot2(__builtin_bit_cast(h2, w), f, acc, false);
#else
    h2 v = __builtin_bit_cast(h2, w);
    return fmaf((float)v.y, (float)f.y, fmaf((float)v.x, (float)f.x, acc));
#endif
}

__device__ __forceinline__ unsigned PK(float lo, float hi) {
    return __builtin_bit_cast(unsigned, __builtin_amdgcn_cvt_pkrtz(lo, hi));
}

__device__ __forceinline__ unsigned ROR16(unsigned v) { return (v >> 16) | (v << 16); }

// wave-internal LDS ordering only — NO barrier (waves are independent)
__device__ __forceinline__ void wave_lgkm0() {
    asm volatile("s_waitcnt lgkmcnt(0)" ::: "memory");
}

// One group (4 outputs i=4g..4g+3) of one DWT level, f16-pair layout.
// Buffer: pair P[k] at u32 index 8+k; front pads P[-7..-1], tail pads per level.
// Window: w[m] = P[4g-8+m], m=0..11; out j uses w[j+1+c], c=0..7.
template<int M, bool STORE>
__device__ __forceinline__ float level_group(const unsigned* __restrict__ inb,
                                             unsigned* __restrict__ outb, int g)
{
    constexpr h2 FA[8] = {
        H2C(0.05441584224308161, 0.3128715909144659),
        H2C(0.6756307362980128, 0.5853546836548691),
        H2C(-0.015829105256023893, -0.2840155429624281),
        H2C(0.00047248457399797254, 0.128747426620186),
        H2C(-0.01736930100202211, -0.04408825393106472),
        H2C(0.013981027917015516, 0.008746094047015655),
        H2C(-0.00487035299301066, -0.0003917403729959771),
        H2C(0.0006754494059985568, -0.00011747678400228192)
    };
    constexpr h2 FD[8] = {
        H2C(-0.00011747678400228192, -0.0006754494059985568),
        H2C(-0.0003917403729959771, 0.00487035299301066),
        H2C(0.008746094047015655, -0.013981027917015516),
        H2C(-0.04408825393106472, 0.01736930100202211),
        H2C(0.128747426620186, -0.00047248457399797254),
        H2C(-0.2840155429624281, 0.015829105256023893),
        H2C(0.5853546836548691, -0.6756307362980128),
        H2C(0.3128715909144659, -0.05441584224308161)
    };
    const uint4 q0 = *(const uint4*)(inb + 4 * g);
    const uint4 q1 = *(const uint4*)(inb + 4 * g + 4);
    const uint4 q2 = *(const uint4*)(inb + 4 * g + 8);
    const unsigned w[12] = {q0.x,q0.y,q0.z,q0.w, q1.x,q1.y,q1.z,q1.w, q2.x,q2.y,q2.z,q2.w};

    float aj[4] = {0.f,0.f,0.f,0.f}, dj[4] = {0.f,0.f,0.f,0.f};
#pragma unroll
    for (int c = 0; c < 8; ++c) {
#pragma unroll
        for (int j = 0; j < 4; ++j) {
            aj[j] = DOT2(w[j+1+c], FA[c], aj[j]);
            dj[j] = DOT2(w[j+1+c], FD[c], dj[j]);
        }
    }
    const int i0 = 4 * g;
    float ds = dj[0] * dj[0];                 // i0 < M always
    if (i0 + 1 < M) ds += dj[1] * dj[1];
    if (i0 + 2 < M) ds += dj[2] * dj[2];
    if (i0 + 3 < M) ds += dj[3] * dj[3];
    if (STORE) {
        // s_next[i]=a_i -> Pn[2g]=(a0,a1), Pn[2g+1]=(a2,a3); tail garbage fixed by fixup
        *(uint2*)(outb + 8 + 2 * g) = make_uint2(PK(aj[0], aj[1]), PK(aj[2], aj[3]));
    }
    return ds;
}

// fixups (wave-internal; caller brackets with wave_lgkm0):
// front: P[-c] = swap(P[c-1]), c=1..7
__device__ __forceinline__ void fix_front(unsigned* b, int lane) {
    if (lane < 7) b[7 - lane] = ROR16(b[8 + lane]);
}
// even-length tail (L0, half-len HL): P[HL+c] = swap(P[HL-1-c]), c=0..6
__device__ __forceinline__ void fix_tail_even(unsigned* b, int lane, int HL) {
    if (lane < 7) b[8 + HL + lane] = ROR16(b[8 + HL - 1 - lane]);
}
// odd-length tail (q=(M-1)/2): P[q].y=P[q].x; P[q+c]=swap(P[q-c]), c=1..7
__device__ __forceinline__ void fix_tail_odd(unsigned* b, int lane, int q) {
    if (lane < 7) b[8 + q + 1 + lane] = ROR16(b[8 + q - 1 - lane]);
    if (lane == 7) { unsigned v = b[8 + q]; b[8 + q] = (v & 0xffffu) | (v << 16); }
}

__global__ __launch_bounds__(256) void combined_loss_kernel(
    const float* __restrict__ x, const float* __restrict__ y,
    float* __restrict__ partials)
{
    // per-wave u32 pair buffers: B0[528] B1[276] B2[152] = 956 u32 = 3824 B/wave
    __shared__ __align__(16) unsigned lds[4][956];
    __shared__ float wsum[4];

    const int tid  = threadIdx.x;
    const int wid  = tid >> 6;
    const int lane = tid & 63;
    unsigned* const W  = lds[wid];
    unsigned* const B0 = W;          // L=1024: 8 front + 512 data + 8 tail
    unsigned* const B1 = W + 528;    // M=519:  8 + 260 + 8
    unsigned* const B2 = W + 804;    // M=267:  8 + 134 + 10

    const int row = blockIdx.x * 4 + wid;
    const float4* xp = (const float4*)x + (size_t)row * 256;
    const float4* yp = (const float4*)y + (size_t)row * 256;

    float4 xc[4];
    float s_mse = 0.f, s_spec = 0.f;

#pragma unroll
    for (int c = 0; c < 4; ++c) {
        const float4 xv = xp[c * 64 + lane];
        const float4 yv = yp[c * 64 + lane];
        xc[c] = xv;
        const float4 ev = make_float4(xv.x - yv.x, xv.y - yv.y, xv.z - yv.z, xv.w - yv.w);
        s_mse += ev.x * ev.x + ev.y * ev.y + ev.z * ev.z + ev.w * ev.w;
        const int u = c * 64 + lane;
        *(uint2*)(B0 + 8 + 2 * u) = make_uint2(PK(ev.x, ev.y), PK(ev.z, ev.w));
    }

    // spectral: sd_i = x[i]-2x[i+1]+x[i+2]; lane owns i=4u..4u+3 (u=64c+lane), i<=1021 (f32 exact)
#pragma unroll
    for (int c = 0; c < 4; ++c) {
        const float4 xv = xc[c];
        float n0 = __shfl_down(xv.x, 1, 64);
        float n1 = __shfl_down(xv.y, 1, 64);
        if (c < 3) {
            const float b0 = __shfl(xc[c + 1].x, 0, 64);
            const float b1 = __shfl(xc[c + 1].y, 0, 64);
            if (lane == 63) { n0 = b0; n1 = b1; }
        }
        const float sd0 = xv.x - 2.f * xv.y + xv.z;
        const float sd1 = xv.y - 2.f * xv.z + xv.w;
        s_spec += sd0 * sd0 + sd1 * sd1;
        const float sd2 = xv.z - 2.f * xv.w + n0;
        const float sd3 = xv.w - 2.f * n0 + n1;
        if (c < 3 || lane < 63)
            s_spec += sd2 * sd2 + sd3 * sd3;
    }

    float s_d1 = 0.f, s_d2 = 0.f, s_d3 = 0.f;

    wave_lgkm0();
    fix_front(B0, lane); fix_tail_even(B0, lane, 512);
    wave_lgkm0();

    for (int g = lane; g < 130; g += 64) s_d1 += level_group<519, true>(B0, B1, g);
    wave_lgkm0();
    fix_front(B1, lane); fix_tail_odd(B1, lane, 259);
    wave_lgkm0();

    for (int g = lane; g < 67; g += 64)  s_d2 += level_group<267, true>(B1, B2, g);
    wave_lgkm0();
    fix_front(B2, lane); fix_tail_odd(B2, lane, 133);
    wave_lgkm0();

    if (lane < 36)                       s_d3 += level_group<141, false>(B2, B2, lane);

    const float wm  = 1.0f / 33554432.0f;             // 32*1024*1024
    const float wsp = 1.0f / 33488896.0f;             // 32*1024*1022
    const float w1  = 1.0f / (3.0f * 17006592.0f);    // 32768*519
    const float w2  = 1.0f / (3.0f * 8749056.0f);     // 32768*267
    const float w3  = 1.0f / (3.0f * 4620288.0f);     // 32768*141
    float local = wm * s_mse + wsp * s_spec + w1 * s_d1 + w2 * s_d2 + w3 * s_d3;

#pragma unroll
    for (int off = 32; off > 0; off >>= 1)
        local += __shfl_down(local, off, 64);
    if (lane == 0) wsum[wid] = local;
    __syncthreads();
    if (tid == 0) partials[blockIdx.x] = wsum[0] + wsum[1] + wsum[2] + wsum[3];
}

__global__ __launch_bounds__(256) void reduce_kernel(const float* __restrict__ partials,
                                                     int n, float* __restrict__ out)
{
    __shared__ double sm[256];
    double s = 0.0;
    for (int i = threadIdx.x; i < n; i += 256) s += (double)partials[i];
    sm[threadIdx.x] = s;
    __syncthreads();
    for (int off = 128; off > 0; off >>= 1) {
        if (threadIdx.x < off) sm[threadIdx.x] += sm[threadIdx.x + off];
        __syncthreads();
    }
    if (threadIdx.x == 0) out[0] = (float)sm[0];
}

extern "C" void kernel_launch(void* const* d_in, const int* in_sizes, int n_in,
                              void* d_out, int out_size, void* d_ws, size_t ws_size,
                              hipStream_t stream) {
    const float* x = (const float*)d_in[0];   // output
    const float* y = (const float*)d_in[1];   // target
    float* partials = (float*)d_ws;           // NBLK floats (32 KB)
    combined_loss_kernel<<<NBLK, 256, 0, stream>>>(x, y, partials);
    reduce_kernel<<<1, 256, 0, stream>>>(partials, NBLK, (float*)d_out);
}

// Round 6
// 54.460 us; speedup vs baseline: 3.2339x; 1.0141x over previous
//
#include <hip/hip_runtime.h>

#define NROWS 32768
#define NBLK  4096   // 4 waves/block, 2 rows per wave

typedef _Float16 h2 __attribute__((ext_vector_type(2)));

// db8 dec filters, pre-reversed (out[i] = sum_k in[2i+k-14]*F[k]), packed as f16 pairs
#define H2C(a,b) {(_Float16)(a##f), (_Float16)(b##f)}

__device__ __forceinline__ float DOT2(unsigned w, h2 f, float acc) {
#if __has_builtin(__builtin_amdgcn_fdot2)
    return __builtin_amdgcn_fdot2(__builtin_bit_cast(h2, w), f, acc, false);
#else
    h2 v = __builtin_bit_cast(h2, w);
    return fmaf((float)v.y, (float)f.y, fmaf((float)v.x, (float)f.x, acc));
#endif
}

__device__ __forceinline__ unsigned PK(float lo, float hi) {
    return __builtin_bit_cast(unsigned, __builtin_amdgcn_cvt_pkrtz(lo, hi));
}

__device__ __forceinline__ unsigned ROR16(unsigned v) { return (v >> 16) | (v << 16); }

// wave-internal LDS ordering only — NO barrier (waves are independent)
__device__ __forceinline__ void wave_lgkm0() {
    asm volatile("s_waitcnt lgkmcnt(0)" ::: "memory");
}

// One group (4 outputs i=4g..4g+3) of one DWT level, f16-pair layout.
// Buffer: pair P[k] at u32 index 8+k; front pads P[-7..-1], tail pads per level.
// Window: w[m] = P[4g-8+m], m=0..11; out j uses w[j+1+c], c=0..7.
template<int M, bool STORE>
__device__ __forceinline__ float level_group(const unsigned* __restrict__ inb,
                                             unsigned* __restrict__ outb, int g)
{
    constexpr h2 FA[8] = {
        H2C(0.05441584224308161, 0.3128715909144659),
        H2C(0.6756307362980128, 0.5853546836548691),
        H2C(-0.015829105256023893, -0.2840155429624281),
        H2C(0.00047248457399797254, 0.128747426620186),
        H2C(-0.01736930100202211, -0.04408825393106472),
        H2C(0.013981027917015516, 0.008746094047015655),
        H2C(-0.00487035299301066, -0.0003917403729959771),
        H2C(0.0006754494059985568, -0.00011747678400228192)
    };
    constexpr h2 FD[8] = {
        H2C(-0.00011747678400228192, -0.0006754494059985568),
        H2C(-0.0003917403729959771, 0.00487035299301066),
        H2C(0.008746094047015655, -0.013981027917015516),
        H2C(-0.04408825393106472, 0.01736930100202211),
        H2C(0.128747426620186, -0.00047248457399797254),
        H2C(-0.2840155429624281, 0.015829105256023893),
        H2C(0.5853546836548691, -0.6756307362980128),
        H2C(0.3128715909144659, -0.05441584224308161)
    };
    const uint4 q0 = *(const uint4*)(inb + 4 * g);
    const uint4 q1 = *(const uint4*)(inb + 4 * g + 4);
    const uint4 q2 = *(const uint4*)(inb + 4 * g + 8);
    const unsigned w[12] = {q0.x,q0.y,q0.z,q0.w, q1.x,q1.y,q1.z,q1.w, q2.x,q2.y,q2.z,q2.w};

    float aj[4] = {0.f,0.f,0.f,0.f}, dj[4] = {0.f,0.f,0.f,0.f};
#pragma unroll
    for (int c = 0; c < 8; ++c) {
#pragma unroll
        for (int j = 0; j < 4; ++j) {
            aj[j] = DOT2(w[j+1+c], FA[c], aj[j]);
            dj[j] = DOT2(w[j+1+c], FD[c], dj[j]);
        }
    }
    const int i0 = 4 * g;
    float ds = dj[0] * dj[0];                 // i0 < M always
    if (i0 + 1 < M) ds += dj[1] * dj[1];
    if (i0 + 2 < M) ds += dj[2] * dj[2];
    if (i0 + 3 < M) ds += dj[3] * dj[3];
    if (STORE) {
        *(uint2*)(outb + 8 + 2 * g) = make_uint2(PK(aj[0], aj[1]), PK(aj[2], aj[3]));
    }
    return ds;
}

// fixups (wave-internal; caller brackets with wave_lgkm0). l must satisfy 0<=l<7 to act.
__device__ __forceinline__ void fix_front(unsigned* b, int l) {
    if ((unsigned)l < 7u) b[7 - l] = ROR16(b[8 + l]);
}
__device__ __forceinline__ void fix_tail_even(unsigned* b, int l, int HL) {
    if ((unsigned)l < 7u) b[8 + HL + l] = ROR16(b[8 + HL - 1 - l]);
}
__device__ __forceinline__ void fix_tail_odd(unsigned* b, int l, int q) {
    if ((unsigned)l < 7u) b[8 + q + 1 + l] = ROR16(b[8 + q - 1 - l]);
    if (l == 7) { unsigned v = b[8 + q]; b[8 + q] = (v & 0xffffu) | (v << 16); }
}

// spectral for one row held in registers: sd_i = x[i]-2x[i+1]+x[i+2], i<=1021 (f32 exact)
__device__ __forceinline__ float spectral_row(const float4* xc, int lane) {
    float s = 0.f;
#pragma unroll
    for (int c = 0; c < 4; ++c) {
        const float4 xv = xc[c];
        float n0 = __shfl_down(xv.x, 1, 64);
        float n1 = __shfl_down(xv.y, 1, 64);
        if (c < 3) {
            const float b0 = __shfl(xc[c + 1].x, 0, 64);
            const float b1 = __shfl(xc[c + 1].y, 0, 64);
            if (lane == 63) { n0 = b0; n1 = b1; }
        }
        const float sd0 = xv.x - 2.f * xv.y + xv.z;
        const float sd1 = xv.y - 2.f * xv.z + xv.w;
        s += sd0 * sd0 + sd1 * sd1;
        const float sd2 = xv.z - 2.f * xv.w + n0;
        const float sd3 = xv.w - 2.f * n0 + n1;
        if (c < 3 || lane < 63)
            s += sd2 * sd2 + sd3 * sd3;
    }
    return s;
}

__global__ __launch_bounds__(256) void combined_loss_kernel(
    const float* __restrict__ x, const float* __restrict__ y,
    float* __restrict__ partials)
{
    // per-row u32 pair buffers: B0[528] B1[276] B2[152] = 956 u32; 2 rows/wave, 4 waves
    __shared__ __align__(16) unsigned lds[8][956];
    __shared__ float wsum[4];

    const int tid  = threadIdx.x;
    const int wid  = tid >> 6;
    const int lane = tid & 63;
    unsigned* const W0 = lds[wid * 2];       // row 0 of this wave
    unsigned* const W1 = lds[wid * 2 + 1];   // row 1

    const int row0 = (blockIdx.x * 4 + wid) * 2;
    const float4* xp0 = (const float4*)x + (size_t)row0 * 256;
    const float4* yp0 = (const float4*)y + (size_t)row0 * 256;
    const float4* xp1 = xp0 + 256;
    const float4* yp1 = yp0 + 256;

    // prefetch both rows (16 global_load_dwordx4 in flight)
    float4 x0[4], y0[4], x1[4], y1[4];
#pragma unroll
    for (int c = 0; c < 4; ++c) {
        x0[c] = xp0[c * 64 + lane];  y0[c] = yp0[c * 64 + lane];
        x1[c] = xp1[c * 64 + lane];  y1[c] = yp1[c * 64 + lane];
    }

    float s_mse = 0.f, s_spec = 0.f;
#pragma unroll
    for (int c = 0; c < 4; ++c) {
        const int u = c * 64 + lane;
        const float4 e0 = make_float4(x0[c].x - y0[c].x, x0[c].y - y0[c].y,
                                      x0[c].z - y0[c].z, x0[c].w - y0[c].w);
        s_mse += e0.x * e0.x + e0.y * e0.y + e0.z * e0.z + e0.w * e0.w;
        *(uint2*)(W0 + 8 + 2 * u) = make_uint2(PK(e0.x, e0.y), PK(e0.z, e0.w));
        const float4 e1 = make_float4(x1[c].x - y1[c].x, x1[c].y - y1[c].y,
                                      x1[c].z - y1[c].z, x1[c].w - y1[c].w);
        s_mse += e1.x * e1.x + e1.y * e1.y + e1.z * e1.z + e1.w * e1.w;
        *(uint2*)(W1 + 8 + 2 * u) = make_uint2(PK(e1.x, e1.y), PK(e1.z, e1.w));
    }

    s_spec += spectral_row(x0, lane);
    s_spec += spectral_row(x1, lane);

    float s_d1 = 0.f, s_d2 = 0.f, s_d3 = 0.f;

    wave_lgkm0();
    fix_front(W0, lane);      fix_tail_even(W0, lane - 16, 512);
    fix_front(W1, lane - 32); fix_tail_even(W1, lane - 48, 512);
    wave_lgkm0();

    for (int g = lane; g < 260; g += 64) {           // L1: both rows, 519 outputs each
        const int r = g >= 130;
        const int gg = g - (r ? 130 : 0);
        unsigned* const W = r ? W1 : W0;
        s_d1 += level_group<519, true>(W, W + 528, gg);
    }
    wave_lgkm0();
    fix_front(W0 + 528, lane);      fix_tail_odd(W0 + 528, lane - 16, 259);
    fix_front(W1 + 528, lane - 32); fix_tail_odd(W1 + 528, lane - 48, 259);
    wave_lgkm0();

    for (int g = lane; g < 134; g += 64) {           // L2: 267 outputs each
        const int r = g >= 67;
        const int gg = g - (r ? 67 : 0);
        unsigned* const W = r ? W1 : W0;
        s_d2 += level_group<267, true>(W + 528, W + 804, gg);
    }
    wave_lgkm0();
    fix_front(W0 + 804, lane);      fix_tail_odd(W0 + 804, lane - 16, 133);
    fix_front(W1 + 804, lane - 32); fix_tail_odd(W1 + 804, lane - 48, 133);
    wave_lgkm0();

    for (int g = lane; g < 72; g += 64) {            // L3: 141 outputs each, cD only
        const int r = g >= 36;
        const int gg = g - (r ? 36 : 0);
        unsigned* const W = r ? W1 : W0;
        s_d3 += level_group<141, false>(W + 804, W + 804, gg);
    }

    const float wm  = 1.0f / 33554432.0f;             // 32*1024*1024
    const float wsp = 1.0f / 33488896.0f;             // 32*1024*1022
    const float w1  = 1.0f / (3.0f * 17006592.0f);    // 32768*519
    const float w2  = 1.0f / (3.0f * 8749056.0f);     // 32768*267
    const float w3  = 1.0f / (3.0f * 4620288.0f);     // 32768*141
    float local = wm * s_mse + wsp * s_spec + w1 * s_d1 + w2 * s_d2 + w3 * s_d3;

#pragma unroll
    for (int off = 32; off > 0; off >>= 1)
        local += __shfl_down(local, off, 64);
    if (lane == 0) wsum[wid] = local;
    __syncthreads();
    if (tid == 0) partials[blockIdx.x] = wsum[0] + wsum[1] + wsum[2] + wsum[3];
}

__global__ __launch_bounds__(256) void reduce_kernel(const float* __restrict__ partials,
                                                     int n, float* __restrict__ out)
{
    __shared__ double sm[256];
    double s = 0.0;
    for (int i = threadIdx.x; i < n; i += 256) s += (double)partials[i];
    sm[threadIdx.x] = s;
    __syncthreads();
    for (int off = 128; off > 0; off >>= 1) {
        if (threadIdx.x < off) sm[threadIdx.x] += sm[threadIdx.x + off];
        __syncthreads();
    }
    if (threadIdx.x == 0) out[0] = (float)sm[0];
}

extern "C" void kernel_launch(void* const* d_in, const int* in_sizes, int n_in,
                              void* d_out, int out_size, void* d_ws, size_t ws_size,
                              hipStream_t stream) {
    const float* x = (const float*)d_in[0];   // output
    const float* y = (const float*)d_in[1];   // target
    float* partials = (float*)d_ws;           // NBLK floats (16 KB)
    combined_loss_kernel<<<NBLK, 256, 0, stream>>>(x, y, partials);
    reduce_kernel<<<1, 256, 0, stream>>>(partials, NBLK, (float*)d_out);
}

// Round 7
// 54.289 us; speedup vs baseline: 3.2441x; 1.0031x over previous
//
#include <hip/hip_runtime.h>

#define NROWS 32768
#define NBLK  2048   // 4 waves/block, 4 rows per wave (pipelined)
#define RPW   4

typedef _Float16 h2 __attribute__((ext_vector_type(2)));

// db8 dec filters, pre-reversed (out[i] = sum_k in[2i+k-14]*F[k]), packed as f16 pairs
#define H2C(a,b) {(_Float16)(a##f), (_Float16)(b##f)}

__device__ __forceinline__ float DOT2(unsigned w, h2 f, float acc) {
#if __has_builtin(__builtin_amdgcn_fdot2)
    return __builtin_amdgcn_fdot2(__builtin_bit_cast(h2, w), f, acc, false);
#else
    h2 v = __builtin_bit_cast(h2, w);
    return fmaf((float)v.y, (float)f.y, fmaf((float)v.x, (float)f.x, acc));
#endif
}

__device__ __forceinline__ unsigned PK(float lo, float hi) {
    return __builtin_bit_cast(unsigned, __builtin_amdgcn_cvt_pkrtz(lo, hi));
}

__device__ __forceinline__ unsigned ROR16(unsigned v) { return (v >> 16) | (v << 16); }

// wave-internal LDS ordering only — NO barrier (waves are independent).
// Waits lgkm only: outstanding global loads (vmcnt) stay in flight.
__device__ __forceinline__ void wave_lgkm0() {
    asm volatile("s_waitcnt lgkmcnt(0)" ::: "memory");
}

// One group (4 outputs i=4g..4g+3) of one DWT level, f16-pair layout.
// Buffer: pair P[k] at u32 index 8+k; front pads P[-7..-1], tail pads per level.
// Window: w[m] = P[4g-8+m], m=0..11; out j uses w[j+1+c], c=0..7.
template<int M, bool STORE>
__device__ __forceinline__ float level_group(const unsigned* __restrict__ inb,
                                             unsigned* __restrict__ outb, int g)
{
    constexpr h2 FA[8] = {
        H2C(0.05441584224308161, 0.3128715909144659),
        H2C(0.6756307362980128, 0.5853546836548691),
        H2C(-0.015829105256023893, -0.2840155429624281),
        H2C(0.00047248457399797254, 0.128747426620186),
        H2C(-0.01736930100202211, -0.04408825393106472),
        H2C(0.013981027917015516, 0.008746094047015655),
        H2C(-0.00487035299301066, -0.0003917403729959771),
        H2C(0.0006754494059985568, -0.00011747678400228192)
    };
    constexpr h2 FD[8] = {
        H2C(-0.00011747678400228192, -0.0006754494059985568),
        H2C(-0.0003917403729959771, 0.00487035299301066),
        H2C(0.008746094047015655, -0.013981027917015516),
        H2C(-0.04408825393106472, 0.01736930100202211),
        H2C(0.128747426620186, -0.00047248457399797254),
        H2C(-0.2840155429624281, 0.015829105256023893),
        H2C(0.5853546836548691, -0.6756307362980128),
        H2C(0.3128715909144659, -0.05441584224308161)
    };
    const uint4 q0 = *(const uint4*)(inb + 4 * g);
    const uint4 q1 = *(const uint4*)(inb + 4 * g + 4);
    const uint4 q2 = *(const uint4*)(inb + 4 * g + 8);
    const unsigned w[12] = {q0.x,q0.y,q0.z,q0.w, q1.x,q1.y,q1.z,q1.w, q2.x,q2.y,q2.z,q2.w};

    float aj[4] = {0.f,0.f,0.f,0.f}, dj[4] = {0.f,0.f,0.f,0.f};
#pragma unroll
    for (int c = 0; c < 8; ++c) {
#pragma unroll
        for (int j = 0; j < 4; ++j) {
            aj[j] = DOT2(w[j+1+c], FA[c], aj[j]);
            dj[j] = DOT2(w[j+1+c], FD[c], dj[j]);
        }
    }
    const int i0 = 4 * g;
    float ds = dj[0] * dj[0];                 // i0 < M always
    if (i0 + 1 < M) ds += dj[1] * dj[1];
    if (i0 + 2 < M) ds += dj[2] * dj[2];
    if (i0 + 3 < M) ds += dj[3] * dj[3];
    if (STORE) {
        *(uint2*)(outb + 8 + 2 * g) = make_uint2(PK(aj[0], aj[1]), PK(aj[2], aj[3]));
    }
    return ds;
}

// fixups (wave-internal; caller brackets with wave_lgkm0). l must satisfy 0<=l<7 to act.
__device__ __forceinline__ void fix_front(unsigned* b, int l) {
    if ((unsigned)l < 7u) b[7 - l] = ROR16(b[8 + l]);
}
__device__ __forceinline__ void fix_tail_even(unsigned* b, int l, int HL) {
    if ((unsigned)l < 7u) b[8 + HL + l] = ROR16(b[8 + HL - 1 - l]);
}
__device__ __forceinline__ void fix_tail_odd(unsigned* b, int l, int q) {
    if ((unsigned)l < 7u) b[8 + q + 1 + l] = ROR16(b[8 + q - 1 - l]);
    if (l == 7) { unsigned v = b[8 + q]; b[8 + q] = (v & 0xffffu) | (v << 16); }
}

// spectral for one row held in registers: sd_i = x[i]-2x[i+1]+x[i+2], i<=1021 (f32 exact)
__device__ __forceinline__ float spectral_row(const float4* xc, int lane) {
    float s = 0.f;
#pragma unroll
    for (int c = 0; c < 4; ++c) {
        const float4 xv = xc[c];
        float n0 = __shfl_down(xv.x, 1, 64);
        float n1 = __shfl_down(xv.y, 1, 64);
        if (c < 3) {
            const float b0 = __shfl(xc[c + 1].x, 0, 64);
            const float b1 = __shfl(xc[c + 1].y, 0, 64);
            if (lane == 63) { n0 = b0; n1 = b1; }
        }
        const float sd0 = xv.x - 2.f * xv.y + xv.z;
        const float sd1 = xv.y - 2.f * xv.z + xv.w;
        s += sd0 * sd0 + sd1 * sd1;
        const float sd2 = xv.z - 2.f * xv.w + n0;
        const float sd3 = xv.w - 2.f * n0 + n1;
        if (c < 3 || lane < 63)
            s += sd2 * sd2 + sd3 * sd3;
    }
    return s;
}

__global__ __launch_bounds__(256) void combined_loss_kernel(
    const float* __restrict__ x, const float* __restrict__ y,
    float* __restrict__ partials)
{
    // per-wave u32 pair buffers: B0[528] B1[276] B2[152] = 956 u32 = 3824 B/wave
    __shared__ __align__(16) unsigned lds[4][956];
    __shared__ float wsum[4];

    const int tid  = threadIdx.x;
    const int wid  = tid >> 6;
    const int lane = tid & 63;
    unsigned* const W  = lds[wid];
    unsigned* const B0 = W;          // L=1024: 8 front + 512 data + 8 tail
    unsigned* const B1 = W + 528;    // M=519:  8 + 260 + 8
    unsigned* const B2 = W + 804;    // M=267:  8 + 134 + 10

    const int rbase = (blockIdx.x * 4 + wid) * RPW;
    const float4* xp = (const float4*)x + (size_t)rbase * 256;
    const float4* yp = (const float4*)y + (size_t)rbase * 256;

    float4 xc[4], yc[4];
#pragma unroll
    for (int c = 0; c < 4; ++c) {
        xc[c] = xp[c * 64 + lane];
        yc[c] = yp[c * 64 + lane];
    }

    float s_mse = 0.f, s_spec = 0.f, s_d1 = 0.f, s_d2 = 0.f, s_d3 = 0.f;

#pragma unroll 1
    for (int k = 0; k < RPW; ++k) {
        // stage current row (consumes yc; xc kept for spectral)
#pragma unroll
        for (int c = 0; c < 4; ++c) {
            const int u = c * 64 + lane;
            const float4 e = make_float4(xc[c].x - yc[c].x, xc[c].y - yc[c].y,
                                         xc[c].z - yc[c].z, xc[c].w - yc[c].w);
            s_mse += e.x * e.x + e.y * e.y + e.z * e.z + e.w * e.w;
            *(uint2*)(B0 + 8 + 2 * u) = make_uint2(PK(e.x, e.y), PK(e.z, e.w));
        }
        s_spec += spectral_row(xc, lane);

        // prefetch next row; loads stay in flight across all three levels (lgkm-only waits below)
        if (k + 1 < RPW) {
            const float4* xpn = xp + (size_t)(k + 1) * 256;
            const float4* ypn = yp + (size_t)(k + 1) * 256;
#pragma unroll
            for (int c = 0; c < 4; ++c) {
                xc[c] = xpn[c * 64 + lane];
                yc[c] = ypn[c * 64 + lane];
            }
        }

        wave_lgkm0();
        fix_front(B0, lane); fix_tail_even(B0, lane - 16, 512);
        wave_lgkm0();
        for (int g = lane; g < 130; g += 64) s_d1 += level_group<519, true>(B0, B1, g);
        wave_lgkm0();
        fix_front(B1, lane); fix_tail_odd(B1, lane - 16, 259);
        wave_lgkm0();
        for (int g = lane; g < 67; g += 64)  s_d2 += level_group<267, true>(B1, B2, g);
        wave_lgkm0();
        fix_front(B2, lane); fix_tail_odd(B2, lane - 16, 133);
        wave_lgkm0();
        if (lane < 36)                       s_d3 += level_group<141, false>(B2, B2, lane);
        // next iteration's B0 staging: same-wave DS ops execute in order -> no hazard
    }

    const float wm  = 1.0f / 33554432.0f;             // 32*1024*1024
    const float wsp = 1.0f / 33488896.0f;             // 32*1024*1022
    const float w1  = 1.0f / (3.0f * 17006592.0f);    // 32768*519
    const float w2  = 1.0f / (3.0f * 8749056.0f);     // 32768*267
    const float w3  = 1.0f / (3.0f * 4620288.0f);     // 32768*141
    float local = wm * s_mse + wsp * s_spec + w1 * s_d1 + w2 * s_d2 + w3 * s_d3;

#pragma unroll
    for (int off = 32; off > 0; off >>= 1)
        local += __shfl_down(local, off, 64);
    if (lane == 0) wsum[wid] = local;
    __syncthreads();
    if (tid == 0) partials[blockIdx.x] = wsum[0] + wsum[1] + wsum[2] + wsum[3];
}

__global__ __launch_bounds__(256) void reduce_kernel(const float* __restrict__ partials,
                                                     int n, float* __restrict__ out)
{
    __shared__ double sm[256];
    double s = 0.0;
    for (int i = threadIdx.x; i < n; i += 256) s += (double)partials[i];
    sm[threadIdx.x] = s;
    __syncthreads();
    for (int off = 128; off > 0; off >>= 1) {
        if (threadIdx.x < off) sm[threadIdx.x] += sm[threadIdx.x + off];
        __syncthreads();
    }
    if (threadIdx.x == 0) out[0] = (float)sm[0];
}

extern "C" void kernel_launch(void* const* d_in, const int* in_sizes, int n_in,
                              void* d_out, int out_size, void* d_ws, size_t ws_size,
                              hipStream_t stream) {
    const float* x = (const float*)d_in[0];   // output
    const float* y = (const float*)d_in[1];   // target
    float* partials = (float*)d_ws;           // NBLK floats (8 KB)
    combined_loss_kernel<<<NBLK, 256, 0, stream>>>(x, y, partials);
    reduce_kernel<<<1, 256, 0, stream>>>(partials, NBLK, (float*)d_out);
}